// Round 1
// baseline (274.908 us; speedup 1.0000x reference)
//
#include <hip/hip_runtime.h>
#include <math.h>

#define DIM 128
// ws layout (floats):
//   ADT                : [0, 16384)
//   W_i (i=0..64)      : (1+i)*16384, each 16384   (W_0 = I, W_64 used as G_1)
//   G slots A/B        : 66*16384, 67*16384
//   Y_j (j=0..63)      : 68*16384 + j*8192
#define WOFF(i) ((size_t)(1 + (i)) * 16384)
#define GAOFF   ((size_t)66 * 16384)
#define GBOFF   ((size_t)67 * 16384)
#define YOFF    ((size_t)68 * 16384)

__device__ __forceinline__ float4 ld4(const float* p) { return *(const float4*)p; }

// ---------------- K0: build ADT, W_0 = I, Y_0 = x0 -------------------------
__global__ __launch_bounds__(256) void k_prep(const float* __restrict__ t,
                                              const float* __restrict__ x0,
                                              const float* __restrict__ S,
                                              const float* __restrict__ D,
                                              float* __restrict__ ws)
{
    int e = blockIdx.x * 256 + threadIdx.x;          // 0..16383
    float dt = t[1] - t[0];
    int r = e >> 7, c = e & 127;
    float a;
    if (r == c)      { a = -log1pf(expf(D[r])); }                      // -softplus
    else if (r < c)  { a =  S[(r * (2 * DIM - r - 1)) / 2 + (c - r - 1)]; }
    else             { a = -S[(c * (2 * DIM - c - 1)) / 2 + (r - c - 1)]; }
    ws[e] = a * dt;                                   // ADT
    ws[16384 + e] = (r == c) ? 1.0f : 0.0f;           // W_0 = I
    if (e < DIM * 64) ws[YOFF + e] = x0[e];           // Y_0 = x0
}

// ---------------- K1: W_1 = expm(ADT), per-column Taylor -------------------
__global__ __launch_bounds__(128) void k_taylor(const float* __restrict__ adt,
                                                float* __restrict__ w1)
{
    __shared__ float M[DIM * 129];   // row-major, +1 pad -> conflict-free M[r][k]
    __shared__ float v[DIM];
    int c = blockIdx.x, r = threadIdx.x;
    for (int idx = r; idx < DIM * DIM; idx += 128) {
        int rr = idx >> 7, kk = idx & 127;
        M[rr * 129 + kk] = adt[idx];
    }
    float acc = (r == c) ? 1.0f : 0.0f;
    v[r] = acc;
    __syncthreads();
    for (int n = 1; n <= 12; n++) {
        float s = 0.0f;
        #pragma unroll 8
        for (int k = 0; k < DIM; k++) s += M[r * 129 + k] * v[k];
        s /= (float)n;                 // v_n = M v_{n-1} / n  = A^n/n! e_c
        __syncthreads();
        v[r] = s;
        acc += s;
        __syncthreads();
    }
    w1[r * DIM + c] = acc;
}

// ---------------- generic level matmul: C_g = A @ B_g (128x128 @ 128xN) ----
// grid.x = matrix index g, grid.y = 32-col panel. Shared A across blocks.
__device__ __forceinline__ void mm_body(const float* __restrict__ A,
                                        const float* __restrict__ B,
                                        float* __restrict__ C,
                                        int ncols, int cpan,
                                        float* AT, float* Bs)
{
    int tid = threadIdx.x;
    for (int idx = tid; idx < DIM * DIM; idx += 256) {
        int d = idx >> 7, k = idx & 127;
        AT[k * 132 + d] = A[idx];                     // transposed, padded
    }
    for (int idx = tid; idx < DIM * 32; idx += 256) {
        int k = idx >> 5, cc = idx & 31;
        Bs[k * 36 + cc] = B[(size_t)k * ncols + cpan + cc];
    }
    __syncthreads();
    int td = tid & 31, tc = tid >> 5;
    int d0 = td * 4, c0 = tc * 4;
    float acc[4][4] = {};
    #pragma unroll 4
    for (int k = 0; k < DIM; k++) {
        float4 a4 = ld4(&AT[k * 132 + d0]);
        float4 b4 = ld4(&Bs[k * 36 + c0]);
        float a_[4] = {a4.x, a4.y, a4.z, a4.w};
        float b_[4] = {b4.x, b4.y, b4.z, b4.w};
        #pragma unroll
        for (int i = 0; i < 4; i++)
            #pragma unroll
            for (int j = 0; j < 4; j++) acc[i][j] += a_[i] * b_[j];
    }
    #pragma unroll
    for (int i = 0; i < 4; i++) {
        float4 st = make_float4(acc[i][0], acc[i][1], acc[i][2], acc[i][3]);
        *(float4*)&C[(size_t)(d0 + i) * ncols + cpan + c0] = st;
    }
}

__global__ __launch_bounds__(256) void k_mm(const float* __restrict__ A,
                                            const float* __restrict__ B0, int sB,
                                            float* __restrict__ C0, int sC, int ncols)
{
    __shared__ float AT[DIM * 132];
    __shared__ float Bs[DIM * 36];
    const float* B = B0 + (size_t)blockIdx.x * sB;
    float*       C = C0 + (size_t)blockIdx.x * sC;
    mm_body(A, B, C, ncols, blockIdx.y * 32, AT, Bs);
}

// ---------------- Y doubling level: Y_{m+j} = G_m Y_j ; G_{2m} = G_m^2 -----
__global__ __launch_bounds__(256) void k_ylev(const float* __restrict__ G,
                                              float* __restrict__ Ybase, int m,
                                              float* __restrict__ Gnext)
{
    __shared__ float AT[DIM * 132];
    __shared__ float Bs[DIM * 36];
    int bx = blockIdx.x, by = blockIdx.y;
    const float* B; float* C; int ncols, cpan;
    if (bx < m) {
        B = Ybase + (size_t)bx * 8192;
        C = Ybase + (size_t)(m + bx) * 8192;
        ncols = 64; cpan = by * 32;
    } else {
        B = G; C = Gnext;
        ncols = 128; cpan = (bx - m) * 64 + by * 32;
    }
    mm_body(G, B, C, ncols, cpan, AT, Bs);
}

// ---------------- final: out[64j+i] = W_i @ Y_j ----------------------------
// grid (i=64, j=64, rb=2); block computes a 64x64 half-slab.
__global__ __launch_bounds__(256) void k_final(const float* __restrict__ ws,
                                               float* __restrict__ out)
{
    __shared__ float AT[DIM * 68];   // [k][d], d in 0..63 (row-half rb)
    __shared__ float Bs[DIM * 68];   // [k][b]
    int i = blockIdx.x, j = blockIdx.y, rb = blockIdx.z;
    const float* Wp = ws + WOFF(i);
    const float* Yp = ws + YOFF + (size_t)j * 8192;
    float* slab = out + (size_t)(j * 64 + i) * 8192;
    int tid = threadIdx.x;
    for (int idx = tid; idx < 64 * DIM; idx += 256) {
        int d = idx >> 7, k = idx & 127;
        AT[k * 68 + d] = Wp[(size_t)(rb * 64 + d) * DIM + k];
    }
    for (int idx = tid; idx < DIM * 64; idx += 256) {
        Bs[(idx >> 6) * 68 + (idx & 63)] = Yp[idx];
    }
    __syncthreads();
    int td = tid >> 4, tc = tid & 15;     // td 0..15 rows, tc 0..15 cols (coalesced stores)
    int d0 = td * 4, c0 = tc * 4;
    float acc[4][4] = {};
    #pragma unroll 4
    for (int k = 0; k < DIM; k++) {
        float4 a4 = ld4(&AT[k * 68 + d0]);
        float4 b4 = ld4(&Bs[k * 68 + c0]);
        float a_[4] = {a4.x, a4.y, a4.z, a4.w};
        float b_[4] = {b4.x, b4.y, b4.z, b4.w};
        #pragma unroll
        for (int p = 0; p < 4; p++)
            #pragma unroll
            for (int q = 0; q < 4; q++) acc[p][q] += a_[p] * b_[q];
    }
    #pragma unroll
    for (int p = 0; p < 4; p++) {
        float4 st = make_float4(acc[p][0], acc[p][1], acc[p][2], acc[p][3]);
        *(float4*)&slab[(size_t)(rb * 64 + d0 + p) * 64 + c0] = st;
    }
}

extern "C" void kernel_launch(void* const* d_in, const int* in_sizes, int n_in,
                              void* d_out, int out_size, void* d_ws, size_t ws_size,
                              hipStream_t stream)
{
    const float* t  = (const float*)d_in[0];
    const float* x0 = (const float*)d_in[1];
    const float* S  = (const float*)d_in[2];
    const float* D  = (const float*)d_in[3];
    float* out = (float*)d_out;
    float* ws  = (float*)d_ws;

    hipLaunchKernelGGL(k_prep, dim3(64), dim3(256), 0, stream, t, x0, S, D, ws);
    hipLaunchKernelGGL(k_taylor, dim3(128), dim3(128), 0, stream, ws, ws + WOFF(1));

    // W doubling: W_{m+1..2m} = W_m @ W_{1..m}
    for (int m = 1; m <= 32; m <<= 1) {
        hipLaunchKernelGGL(k_mm, dim3(m, 4), dim3(256), 0, stream,
                           ws + WOFF(m), ws + WOFF(1), 16384,
                           ws + WOFF(m + 1), 16384, 128);
    }

    // Y doubling with G_m carried alongside (G_1 = W_64)
    float* g    = ws + WOFF(64);
    float* next = ws + GAOFF;
    float* other= ws + GBOFF;
    for (int m = 1; m <= 32; m <<= 1) {
        int extra = (m < 32) ? 2 : 0;
        hipLaunchKernelGGL(k_ylev, dim3(m + extra, 2), dim3(256), 0, stream,
                           g, ws + YOFF, m, (m < 32) ? next : nullptr);
        if (m < 32) { g = next; float* tmp = next == ws + GAOFF ? other : ws + GAOFF; next = tmp; }
    }

    // out[64j + i] = W_i @ Y_j
    hipLaunchKernelGGL(k_final, dim3(64, 64, 2), dim3(256), 0, stream, ws, out);
}

// Round 2
// 223.048 us; speedup vs baseline: 1.2325x; 1.2325x over previous
//
#include <hip/hip_runtime.h>
#include <math.h>

#define DIM 128
// ws layout (floats):
//   ADT (unused now)   : [0, 16384)
//   W_i f32 (i=0..64)  : (1+i)*16384, each 16384   (W_64 used as G_1)
//   G slots A/B        : 66*16384, 67*16384
//   Y_j f32 (j=0..63)  : 68*16384 + j*8192
//   Wf f16 (i=0..63)   : float offset FWOFF, 64*16384 halves
//   Yf f16 (j=0..63)   : float offset FYOFF, 64*8192 halves
#define WOFF(i) ((size_t)(1 + (i)) * 16384)
#define GAOFF   ((size_t)66 * 16384)
#define GBOFF   ((size_t)67 * 16384)
#define YOFF    ((size_t)68 * 16384)
#define FWOFF   ((size_t)68 * 16384 + 64 * 8192)            // 1638400 floats
#define FYOFF   (FWOFF + 64 * 8192)                          // Wf = 524288 floats worth

typedef _Float16 f16x8 __attribute__((ext_vector_type(8)));
typedef float    f32x4 __attribute__((ext_vector_type(4)));

__device__ __forceinline__ float4 ld4(const float* p) { return *(const float4*)p; }

// ---------------- K0: fused ADT-build + W_1 = expm(ADT) Taylor + Y_0 copy --
__global__ __launch_bounds__(128) void k_taylor(const float* __restrict__ t,
                                                const float* __restrict__ x0,
                                                const float* __restrict__ S,
                                                const float* __restrict__ D,
                                                float* __restrict__ ws)
{
    __shared__ float M[DIM * 129];
    __shared__ float v[DIM];
    int c = blockIdx.x, r = threadIdx.x;
    float dt = t[1] - t[0];
    for (int idx = r; idx < DIM * DIM; idx += 128) {
        int rr = idx >> 7, cc = idx & 127;
        float a;
        if (rr == cc)      a = -log1pf(expf(D[rr]));
        else if (rr < cc)  a =  S[(rr * (2 * DIM - rr - 1)) / 2 + (cc - rr - 1)];
        else               a = -S[(cc * (2 * DIM - cc - 1)) / 2 + (rr - cc - 1)];
        M[rr * 129 + cc] = a * dt;
    }
    if (r < 64) ws[YOFF + (size_t)c * 64 + r] = x0[c * 64 + r];   // Y_0 = x0
    float acc = (r == c) ? 1.0f : 0.0f;
    v[r] = acc;
    __syncthreads();
    for (int n = 1; n <= 12; n++) {
        float s = 0.0f;
        #pragma unroll 8
        for (int k = 0; k < DIM; k++) s += M[r * 129 + k] * v[k];
        s /= (float)n;
        __syncthreads();
        v[r] = s;
        acc += s;
        __syncthreads();
    }
    ws[WOFF(1) + r * DIM + c] = acc;
}

// ---------------- generic level matmul: C_g = A @ B_g (f32, unchanged) ----
__device__ __forceinline__ void mm_body(const float* __restrict__ A,
                                        const float* __restrict__ B,
                                        float* __restrict__ C,
                                        int ncols, int cpan,
                                        float* AT, float* Bs)
{
    int tid = threadIdx.x;
    for (int idx = tid; idx < DIM * DIM; idx += 256) {
        int d = idx >> 7, k = idx & 127;
        AT[k * 132 + d] = A[idx];
    }
    for (int idx = tid; idx < DIM * 32; idx += 256) {
        int k = idx >> 5, cc = idx & 31;
        Bs[k * 36 + cc] = B[(size_t)k * ncols + cpan + cc];
    }
    __syncthreads();
    int td = tid & 31, tc = tid >> 5;
    int d0 = td * 4, c0 = tc * 4;
    float acc[4][4] = {};
    #pragma unroll 4
    for (int k = 0; k < DIM; k++) {
        float4 a4 = ld4(&AT[k * 132 + d0]);
        float4 b4 = ld4(&Bs[k * 36 + c0]);
        float a_[4] = {a4.x, a4.y, a4.z, a4.w};
        float b_[4] = {b4.x, b4.y, b4.z, b4.w};
        #pragma unroll
        for (int i = 0; i < 4; i++)
            #pragma unroll
            for (int j = 0; j < 4; j++) acc[i][j] += a_[i] * b_[j];
    }
    #pragma unroll
    for (int i = 0; i < 4; i++) {
        float4 st = make_float4(acc[i][0], acc[i][1], acc[i][2], acc[i][3]);
        *(float4*)&C[(size_t)(d0 + i) * ncols + cpan + c0] = st;
    }
}

__global__ __launch_bounds__(256) void k_mm(const float* __restrict__ A,
                                            const float* __restrict__ B0, int sB,
                                            float* __restrict__ C0, int sC, int ncols)
{
    __shared__ float AT[DIM * 132];
    __shared__ float Bs[DIM * 36];
    const float* B = B0 + (size_t)blockIdx.x * sB;
    float*       C = C0 + (size_t)blockIdx.x * sC;
    mm_body(A, B, C, ncols, blockIdx.y * 32, AT, Bs);
}

__global__ __launch_bounds__(256) void k_ylev(const float* __restrict__ G,
                                              float* __restrict__ Ybase, int m,
                                              float* __restrict__ Gnext)
{
    __shared__ float AT[DIM * 132];
    __shared__ float Bs[DIM * 36];
    int bx = blockIdx.x, by = blockIdx.y;
    const float* B; float* C; int ncols, cpan;
    if (bx < m) {
        B = Ybase + (size_t)bx * 8192;
        C = Ybase + (size_t)(m + bx) * 8192;
        ncols = 64; cpan = by * 32;
    } else {
        B = G; C = Gnext;
        ncols = 128; cpan = (bx - m) * 64 + by * 32;
    }
    mm_body(G, B, C, ncols, cpan, AT, Bs);
}

// ---------------- convert W_i -> f16 fragment-order table -----------------
// chunk = 8 consecutive k for fixed m. frag addr: ((rb*4+ks)*64 + lane)*8,
// lane = (m&15) | (((k0>>3)&3)<<4), rb = m>>4, ks = k0>>5.
__global__ __launch_bounds__(256) void k_convW(const float* __restrict__ ws,
                                               _Float16* __restrict__ Wf)
{
    int g = blockIdx.x * 256 + threadIdx.x;      // 64 * 2048
    int i = g >> 11, c = g & 2047;
    int m = c >> 4, k0 = (c & 15) << 3;
    float v[8];
    if (i == 0) {
        #pragma unroll
        for (int q = 0; q < 8; q++) v[q] = (m == k0 + q) ? 1.0f : 0.0f;
    } else {
        const float* src = ws + WOFF(i) + (size_t)m * DIM + k0;
        float4 a = ld4(src), b = ld4(src + 4);
        v[0]=a.x; v[1]=a.y; v[2]=a.z; v[3]=a.w; v[4]=b.x; v[5]=b.y; v[6]=b.z; v[7]=b.w;
    }
    f16x8 h;
    #pragma unroll
    for (int q = 0; q < 8; q++) h[q] = (_Float16)v[q];
    int lane = (m & 15) | (((k0 >> 3) & 3) << 4);
    size_t off = (size_t)i * 16384 + (((size_t)(m >> 4) * 4 + (k0 >> 5)) * 64 + lane) * 8;
    *(f16x8*)(Wf + off) = h;
}

// ---------------- convert Y_j -> f16 fragment-order table (B operand) -----
// chunk = 8 consecutive k for fixed n (strided gather from f32 Y).
__global__ __launch_bounds__(256) void k_convY(const float* __restrict__ ws,
                                               _Float16* __restrict__ Yf)
{
    int g = blockIdx.x * 256 + threadIdx.x;      // 64 * 1024
    int j = g >> 10, c = g & 1023;
    int n = c >> 4, k0 = (c & 15) << 3;
    const float* src = ws + YOFF + (size_t)j * 8192 + n;
    f16x8 h;
    #pragma unroll
    for (int q = 0; q < 8; q++) h[q] = (_Float16)src[(size_t)(k0 + q) * 64];
    int lane = (n & 15) | (((k0 >> 3) & 3) << 4);
    size_t off = (size_t)j * 8192 + (((size_t)(n >> 4) * 4 + (k0 >> 5)) * 64 + lane) * 8;
    *(f16x8*)(Yf + off) = h;
}

// ---------------- final: out[64j+i] = W_i @ Y_j via MFMA f16 --------------
// grid (i=64, j=64), 256 thr = 4 waves; wave (wm,wn) owns 64x32 of 128x64.
__global__ __launch_bounds__(256) void k_final(const _Float16* __restrict__ Wf,
                                               const _Float16* __restrict__ Yf,
                                               float* __restrict__ out)
{
    int i = blockIdx.x, j = blockIdx.y;
    int tid = threadIdx.x;
    int wave = tid >> 6, lane = tid & 63;
    int wm = wave >> 1, wn = wave & 1;
    const _Float16* Ab = Wf + (size_t)i * 16384;
    const _Float16* Bb = Yf + (size_t)j * 8192;

    f32x4 acc[4][2] = {};
    #pragma unroll
    for (int ks = 0; ks < 4; ks++) {
        f16x8 a[4], b[2];
        #pragma unroll
        for (int r = 0; r < 4; r++)
            a[r] = *(const f16x8*)(Ab + ((((size_t)(wm * 4 + r)) * 4 + ks) * 64 + lane) * 8);
        #pragma unroll
        for (int nn = 0; nn < 2; nn++)
            b[nn] = *(const f16x8*)(Bb + ((((size_t)(wn * 2 + nn)) * 4 + ks) * 64 + lane) * 8);
        #pragma unroll
        for (int r = 0; r < 4; r++)
            #pragma unroll
            for (int nn = 0; nn < 2; nn++)
                acc[r][nn] = __builtin_amdgcn_mfma_f32_16x16x32_f16(a[r], b[nn], acc[r][nn], 0, 0, 0);
    }

    float* slab = out + (size_t)(j * 64 + i) * 8192;
    int r4 = (lane >> 4) * 4, cn = lane & 15;
    #pragma unroll
    for (int r = 0; r < 4; r++)
        #pragma unroll
        for (int nn = 0; nn < 2; nn++)
            #pragma unroll
            for (int q = 0; q < 4; q++)
                slab[(size_t)(wm * 64 + r * 16 + r4 + q) * 64 + wn * 32 + nn * 16 + cn] = acc[r][nn][q];
}

extern "C" void kernel_launch(void* const* d_in, const int* in_sizes, int n_in,
                              void* d_out, int out_size, void* d_ws, size_t ws_size,
                              hipStream_t stream)
{
    const float* t  = (const float*)d_in[0];
    const float* x0 = (const float*)d_in[1];
    const float* S  = (const float*)d_in[2];
    const float* D  = (const float*)d_in[3];
    float* out = (float*)d_out;
    float* ws  = (float*)d_ws;
    _Float16* Wf = (_Float16*)(ws + FWOFF);
    _Float16* Yf = (_Float16*)(ws + FYOFF);

    hipLaunchKernelGGL(k_taylor, dim3(128), dim3(128), 0, stream, t, x0, S, D, ws);

    // W doubling: W_{m+1..2m} = W_m @ W_{1..m}
    for (int m = 1; m <= 32; m <<= 1) {
        hipLaunchKernelGGL(k_mm, dim3(m, 4), dim3(256), 0, stream,
                           ws + WOFF(m), ws + WOFF(1), 16384,
                           ws + WOFF(m + 1), 16384, 128);
    }
    hipLaunchKernelGGL(k_convW, dim3(512), dim3(256), 0, stream, ws, Wf);

    // Y doubling with G_m carried alongside (G_1 = W_64)
    float* g    = ws + WOFF(64);
    float* next = ws + GAOFF;
    float* other= ws + GBOFF;
    for (int m = 1; m <= 32; m <<= 1) {
        int extra = (m < 32) ? 2 : 0;
        hipLaunchKernelGGL(k_ylev, dim3(m + extra, 2), dim3(256), 0, stream,
                           g, ws + YOFF, m, (m < 32) ? next : nullptr);
        if (m < 32) { g = next; float* tmp = next == ws + GAOFF ? other : ws + GAOFF; next = tmp; }
    }
    hipLaunchKernelGGL(k_convY, dim3(256), dim3(256), 0, stream, ws, Yf);

    // out[64j + i] = W_i @ Y_j   (MFMA f16, frag-order tables, no LDS)
    hipLaunchKernelGGL(k_final, dim3(64, 64), dim3(256), 0, stream, Wf, Yf, out);
}

// Round 4
// 194.277 us; speedup vs baseline: 1.4150x; 1.1481x over previous
//
#include <hip/hip_runtime.h>
#include <math.h>

#define DIM 128
// ws float layout:
//   W[i] f32, i=1..63 : (i-1)*16384
//   G ping-pong s=0,1 : (63+s)*16384     (G_d = E^(64*2^d); E64 lands in s0)
//   Y[j] f32, j=0..63 : YOFFI + j*8192
//   Wf f16 frags      : float idx FWOFFI (64*16384 halves)
//   Yf f16 frags      : float idx FYOFFI (64*8192 halves)
#define WOFFI(i) (((i) - 1) * 16384)
#define GOFFI(s) ((63 + (s)) * 16384)
#define YOFFI    (65 * 16384)
#define FWOFFI   (YOFFI + 64 * 8192)
#define FYOFFI   (FWOFFI + 64 * 8192)

typedef _Float16 f16x8 __attribute__((ext_vector_type(8)));
typedef float    f32x4 __attribute__((ext_vector_type(4)));

__device__ __forceinline__ float4 ld4(const float* p) { return *(const float4*)p; }

// ---- K0: exp(c*X) for c=1,2,4,8,16,32,64 in parallel; also Y0 = x0 --------
// grid (128 cols, 7 scales), block 256 = 2 k-halves x 128 rows.
__global__ __launch_bounds__(256) void k_taylor(const float* __restrict__ t,
                                                const float* __restrict__ x0,
                                                const float* __restrict__ S,
                                                const float* __restrict__ D,
                                                float* __restrict__ ws)
{
    __shared__ __align__(16) float M[DIM * 132];
    __shared__ __align__(16) float v[DIM];
    __shared__ float ps[256];
    const int col = blockIdx.x;          // 0..127
    const int p   = blockIdx.y;          // 0..6 -> c = 1<<p
    const int tid = threadIdx.x;
    const int r = tid & 127, h = tid >> 7;
    const float dt = t[1] - t[0];
    const float cs = (float)(1 << p);
    for (int idx = tid; idx < DIM * DIM; idx += 256) {
        int rr = idx >> 7, cc = idx & 127;
        float a;
        if (rr == cc)      a = -log1pf(expf(D[rr]));
        else if (rr < cc)  a =  S[(rr * (2 * DIM - rr - 1)) / 2 + (cc - rr - 1)];
        else               a = -S[(cc * (2 * DIM - cc - 1)) / 2 + (rr - cc - 1)];
        M[rr * 132 + cc] = a * dt * cs;
    }
    if (p == 0 && h == 0 && r < 64) ws[YOFFI + col * 64 + r] = x0[col * 64 + r];
    if (h == 0) v[r] = (r == col) ? 1.0f : 0.0f;
    float acc = (r == col) ? 1.0f : 0.0f;
    const int NT[7] = {12, 13, 15, 17, 21, 25, 30};
    const int nt = NT[p];
    for (int n = 1; n <= nt; n++) {
        __syncthreads();                              // v ready
        const float4* m4 = (const float4*)&M[r * 132 + h * 64];
        const float4* v4 = (const float4*)&v[h * 64];
        float sa[4] = {0.f, 0.f, 0.f, 0.f};
        #pragma unroll
        for (int q = 0; q < 16; q++) {
            float4 a4 = m4[q], b4 = v4[q];
            sa[q & 3] += a4.x * b4.x + a4.y * b4.y + a4.z * b4.z + a4.w * b4.w;
        }
        ps[tid] = (sa[0] + sa[1]) + (sa[2] + sa[3]);
        __syncthreads();
        if (h == 0) {
            float w = (ps[r] + ps[128 + r]) / (float)n;
            acc += w;
            v[r] = w;
        }
    }
    if (h == 0) {
        int dst = (p < 6) ? WOFFI(1 << p) : GOFFI(0);
        ws[dst + r * DIM + col] = acc;
    }
}

// ---- generic job matmul: C = A(128x128) @ B(128xncols) --------------------
__device__ __forceinline__ void mm_body(const float* __restrict__ A,
                                        const float* __restrict__ B,
                                        float* __restrict__ C,
                                        int ncols, int cpan,
                                        float* AT, float* Bs)
{
    int tid = threadIdx.x;
    for (int idx = tid; idx < DIM * DIM; idx += 256) {
        int d = idx >> 7, k = idx & 127;
        AT[k * 132 + d] = A[idx];
    }
    for (int idx = tid; idx < DIM * 32; idx += 256) {
        int k = idx >> 5, cc = idx & 31;
        Bs[k * 36 + cc] = B[(size_t)k * ncols + cpan + cc];
    }
    __syncthreads();
    int td = tid & 31, tc = tid >> 5;
    int d0 = td * 4, c0 = tc * 4;
    float acc[4][4] = {};
    #pragma unroll 4
    for (int k = 0; k < DIM; k++) {
        float4 a4 = ld4(&AT[k * 132 + d0]);
        float4 b4 = ld4(&Bs[k * 36 + c0]);
        float a_[4] = {a4.x, a4.y, a4.z, a4.w};
        float b_[4] = {b4.x, b4.y, b4.z, b4.w};
        #pragma unroll
        for (int i = 0; i < 4; i++)
            #pragma unroll
            for (int j = 0; j < 4; j++) acc[i][j] += a_[i] * b_[j];
    }
    #pragma unroll
    for (int i = 0; i < 4; i++) {
        float4 st = make_float4(acc[i][0], acc[i][1], acc[i][2], acc[i][3]);
        *(float4*)&C[(size_t)(d0 + i) * ncols + cpan + c0] = st;
    }
}

struct Jobs { int4 jb[56]; };

__global__ __launch_bounds__(256) void k_lvl(float* __restrict__ ws, Jobs jobs)
{
    __shared__ float AT[DIM * 132];
    __shared__ float Bs[DIM * 36];
    int4 jb = jobs.jb[blockIdx.x];
    int ncols = jb.w;
    int cpan = blockIdx.y * 32;
    if (cpan >= ncols) return;
    mm_body(ws + jb.x, ws + jb.y, ws + jb.z, ncols, cpan, AT, Bs);
}

// ---- fused convert: W_i -> Wf frags, Y_j -> Yf frags ----------------------
__global__ __launch_bounds__(256) void k_conv(const float* __restrict__ ws,
                                              _Float16* __restrict__ Wf,
                                              _Float16* __restrict__ Yf)
{
    int g = blockIdx.x * 256 + threadIdx.x;          // 0 .. 196607
    if (g < 131072) {                                // W: 64 mats x 2048 chunks
        int i = g >> 11, c = g & 2047;
        int m = c >> 4, k0 = (c & 15) << 3;
        float v[8];
        if (i == 0) {
            #pragma unroll
            for (int q = 0; q < 8; q++) v[q] = (m == k0 + q) ? 1.0f : 0.0f;
        } else {
            const float* src = ws + WOFFI(i) + (size_t)m * DIM + k0;
            float4 a = ld4(src), b = ld4(src + 4);
            v[0]=a.x; v[1]=a.y; v[2]=a.z; v[3]=a.w; v[4]=b.x; v[5]=b.y; v[6]=b.z; v[7]=b.w;
        }
        f16x8 hv;
        #pragma unroll
        for (int q = 0; q < 8; q++) hv[q] = (_Float16)v[q];
        int lane = (m & 15) | (((k0 >> 3) & 3) << 4);
        size_t off = (size_t)i * 16384 + (((size_t)(m >> 4) * 4 + (k0 >> 5)) * 64 + lane) * 8;
        *(f16x8*)(Wf + off) = hv;
    } else {                                         // Y: 64 mats x 1024 chunks
        int g2 = g - 131072;
        int j = g2 >> 10, c = g2 & 1023;
        int n = c >> 4, k0 = (c & 15) << 3;
        const float* src = ws + YOFFI + (size_t)j * 8192 + n;
        f16x8 hv;
        #pragma unroll
        for (int q = 0; q < 8; q++) hv[q] = (_Float16)src[(size_t)(k0 + q) * 64];
        int lane = (n & 15) | (((k0 >> 3) & 3) << 4);
        size_t off = (size_t)j * 8192 + (((size_t)(n >> 4) * 4 + (k0 >> 5)) * 64 + lane) * 8;
        *(f16x8*)(Yf + off) = hv;
    }
}

// ---- final: out[64j+i] = W_i @ Y_j, computed as C' = Y^T W^T (batch-major)-
// A-frag = Yf (rows=batch), B-frag = Wf (cols=dim) -> lane's 4 acc values are
// batch-consecutive -> dwordx4 nontemporal stores (ext-vector f32x4).
__global__ __launch_bounds__(256) void k_final(const _Float16* __restrict__ Wf,
                                               const _Float16* __restrict__ Yf,
                                               float* __restrict__ out)
{
    int i = blockIdx.x, j = blockIdx.y;
    int tid = threadIdx.x, wave = tid >> 6, lane = tid & 63;
    const _Float16* Ab = Yf + (size_t)j * 8192;
    const _Float16* Bb = Wf + (size_t)i * 16384;
    f32x4 acc[4][2] = {};
    #pragma unroll
    for (int ks = 0; ks < 4; ks++) {
        f16x8 a[4], b[2];
        #pragma unroll
        for (int bt = 0; bt < 4; bt++)
            a[bt] = *(const f16x8*)(Ab + (((size_t)bt * 4 + ks) * 64 + lane) * 8);
        #pragma unroll
        for (int nn = 0; nn < 2; nn++)
            b[nn] = *(const f16x8*)(Bb + (((size_t)(wave * 2 + nn) * 4 + ks) * 64 + lane) * 8);
        #pragma unroll
        for (int bt = 0; bt < 4; bt++)
            #pragma unroll
            for (int nn = 0; nn < 2; nn++)
                acc[bt][nn] = __builtin_amdgcn_mfma_f32_16x16x32_f16(a[bt], b[nn], acc[bt][nn], 0, 0, 0);
    }
    float* slab = out + (size_t)(j * 64 + i) * 8192;
    int nlo = lane & 15, b0 = (lane >> 4) * 4;
    #pragma unroll
    for (int bt = 0; bt < 4; bt++)
        #pragma unroll
        for (int nn = 0; nn < 2; nn++) {
            int n = (wave * 2 + nn) * 16 + nlo;
            __builtin_nontemporal_store(acc[bt][nn],
                (f32x4*)&slab[(size_t)n * 64 + bt * 16 + b0]);
        }
}

static inline void addjob(Jobs& J, int& n, int a, int b, int c, int nc)
{
    J.jb[n++] = make_int4(a, b, c, nc);
}

extern "C" void kernel_launch(void* const* d_in, const int* in_sizes, int n_in,
                              void* d_out, int out_size, void* d_ws, size_t ws_size,
                              hipStream_t stream)
{
    const float* t  = (const float*)d_in[0];
    const float* x0 = (const float*)d_in[1];
    const float* S  = (const float*)d_in[2];
    const float* D  = (const float*)d_in[3];
    float* out = (float*)d_out;
    float* ws  = (float*)d_ws;
    _Float16* Wf = (_Float16*)(ws + FWOFFI);
    _Float16* Yf = (_Float16*)(ws + FYOFFI);

    hipLaunchKernelGGL(k_taylor, dim3(128, 7), dim3(256), 0, stream, t, x0, S, D, ws);

    Jobs J; int n;

    // L1: E3, E12, E48; G1 = E64^2 = E128; Y1 = E64 Y0
    n = 0;
    addjob(J, n, WOFFI(2),  WOFFI(1),  WOFFI(3),  128);
    addjob(J, n, WOFFI(8),  WOFFI(4),  WOFFI(12), 128);
    addjob(J, n, WOFFI(32), WOFFI(16), WOFFI(48), 128);
    addjob(J, n, GOFFI(0),  GOFFI(0),  GOFFI(1),  128);
    addjob(J, n, GOFFI(0),  YOFFI,     YOFFI + 8192, 64);
    hipLaunchKernelGGL(k_lvl, dim3(n, 4), dim3(256), 0, stream, ws, J);

    // L2: W[r] r in {5,6,7,9,10,11,13,14,15}; Y2,Y3 = G1 Y0,Y1; G2 = G1^2
    n = 0;
    {
        const int rs[9] = {5, 6, 7, 9, 10, 11, 13, 14, 15};
        for (int q = 0; q < 9; q++) {
            int r = rs[q];
            addjob(J, n, WOFFI((r >> 2) << 2), WOFFI(r & 3), WOFFI(r), 128);
        }
    }
    addjob(J, n, GOFFI(1), YOFFI,         YOFFI + 2 * 8192, 64);
    addjob(J, n, GOFFI(1), YOFFI + 8192,  YOFFI + 3 * 8192, 64);
    addjob(J, n, GOFFI(1), GOFFI(1), GOFFI(0), 128);
    hipLaunchKernelGGL(k_lvl, dim3(n, 4), dim3(256), 0, stream, ws, J);

    // L3: W[i] i=16..63 (i&15 != 0); Y4..7 = G2 Y0..3; G3 = G2^2
    n = 0;
    for (int i = 17; i < 64; i++) {
        if ((i & 15) == 0) continue;
        addjob(J, n, WOFFI(i & 48), WOFFI(i & 15), WOFFI(i), 128);
    }
    for (int jj = 0; jj < 4; jj++)
        addjob(J, n, GOFFI(0), YOFFI + jj * 8192, YOFFI + (4 + jj) * 8192, 64);
    addjob(J, n, GOFFI(0), GOFFI(0), GOFFI(1), 128);
    hipLaunchKernelGGL(k_lvl, dim3(n, 4), dim3(256), 0, stream, ws, J);

    // L4: Y8..15 = G3 Y0..7; G4 = G3^2
    n = 0;
    for (int jj = 0; jj < 8; jj++)
        addjob(J, n, GOFFI(1), YOFFI + jj * 8192, YOFFI + (8 + jj) * 8192, 64);
    addjob(J, n, GOFFI(1), GOFFI(1), GOFFI(0), 128);
    hipLaunchKernelGGL(k_lvl, dim3(n, 4), dim3(256), 0, stream, ws, J);

    // L5: Y16..31 = G4 Y0..15; G5 = G4^2
    n = 0;
    for (int jj = 0; jj < 16; jj++)
        addjob(J, n, GOFFI(0), YOFFI + jj * 8192, YOFFI + (16 + jj) * 8192, 64);
    addjob(J, n, GOFFI(0), GOFFI(0), GOFFI(1), 128);
    hipLaunchKernelGGL(k_lvl, dim3(n, 4), dim3(256), 0, stream, ws, J);

    // L6: Y32..63 = G5 Y0..31
    n = 0;
    for (int jj = 0; jj < 32; jj++)
        addjob(J, n, GOFFI(1), YOFFI + jj * 8192, YOFFI + (32 + jj) * 8192, 64);
    hipLaunchKernelGGL(k_lvl, dim3(n, 4), dim3(256), 0, stream, ws, J);

    // convert all W,Y -> f16 fragment tables (one launch)
    hipLaunchKernelGGL(k_conv, dim3(768), dim3(256), 0, stream, ws, Wf, Yf);

    // out[64j+i] = W_i @ Y_j
    hipLaunchKernelGGL(k_final, dim3(64, 64), dim3(256), 0, stream, Wf, Yf, out);
}

// Round 5
// 192.964 us; speedup vs baseline: 1.4247x; 1.0068x over previous
//
#include <hip/hip_runtime.h>
#include <math.h>

#define DIM 128
// ws float layout:
//   W[i] f32, i=1..63 : (i-1)*16384          (W_i = E^i)
//   G ping-pong s=0,1 : (63+s)*16384         (E64 -> s0; G1 -> s1; alternating)
//   Y[j] f32, j=0..63 : YOFFI + j*8192
//   X^q (q=1..4)      : XP(q-1) = (69+q-1)*16384
//   Wf f16 frags      : float idx FWOFFI
//   Yf f16 frags      : float idx FYOFFI
#define WOFFI(i) (((i) - 1) * 16384)
#define GOFFI(s) ((63 + (s)) * 16384)
#define YOFFI    (65 * 16384)
#define XP(q)    ((69 + (q)) * 16384)
#define FWOFFI   (73 * 16384)
#define FYOFFI   (FWOFFI + 32 * 16384)

typedef _Float16 f16x8 __attribute__((ext_vector_type(8)));
typedef float    f32x4 __attribute__((ext_vector_type(4)));

__device__ __forceinline__ float4 ld4(const float* p) { return *(const float4*)p; }

// ---- K0: build X = A*dt (f32), Y0 = x0 ------------------------------------
__global__ __launch_bounds__(256) void k_build(const float* __restrict__ t,
                                               const float* __restrict__ x0,
                                               const float* __restrict__ S,
                                               const float* __restrict__ D,
                                               float* __restrict__ ws)
{
    int e = blockIdx.x * 256 + threadIdx.x;          // 0..16383
    float dt = t[1] - t[0];
    int r = e >> 7, c = e & 127;
    float a;
    if (r == c)      a = -log1pf(expf(D[r]));
    else if (r < c)  a =  S[(r * (2 * DIM - r - 1)) / 2 + (c - r - 1)];
    else             a = -S[(c * (2 * DIM - c - 1)) / 2 + (r - c - 1)];
    ws[XP(0) + e] = a * dt;
    if (e < DIM * 64) ws[YOFFI + e] = x0[e];
}

// ---- generic job matmul: C = A(128x128) @ B(128xncols) --------------------
__device__ __forceinline__ void mm_body(const float* __restrict__ A,
                                        const float* __restrict__ B,
                                        float* __restrict__ C,
                                        int ncols, int cpan,
                                        float* AT, float* Bs)
{
    int tid = threadIdx.x;
    for (int idx = tid; idx < DIM * DIM; idx += 256) {
        int d = idx >> 7, k = idx & 127;
        AT[k * 132 + d] = A[idx];
    }
    for (int idx = tid; idx < DIM * 32; idx += 256) {
        int k = idx >> 5, cc = idx & 31;
        Bs[k * 36 + cc] = B[(size_t)k * ncols + cpan + cc];
    }
    __syncthreads();
    int td = tid & 31, tc = tid >> 5;
    int d0 = td * 4, c0 = tc * 4;
    float acc[4][4] = {};
    #pragma unroll 4
    for (int k = 0; k < DIM; k++) {
        float4 a4 = ld4(&AT[k * 132 + d0]);
        float4 b4 = ld4(&Bs[k * 36 + c0]);
        float a_[4] = {a4.x, a4.y, a4.z, a4.w};
        float b_[4] = {b4.x, b4.y, b4.z, b4.w};
        #pragma unroll
        for (int i = 0; i < 4; i++)
            #pragma unroll
            for (int j = 0; j < 4; j++) acc[i][j] += a_[i] * b_[j];
    }
    #pragma unroll
    for (int i = 0; i < 4; i++) {
        float4 st = make_float4(acc[i][0], acc[i][1], acc[i][2], acc[i][3]);
        *(float4*)&C[(size_t)(d0 + i) * ncols + cpan + c0] = st;
    }
}

struct Jobs { int4 jb[56]; };

__global__ __launch_bounds__(256) void k_lvl(float* __restrict__ ws, Jobs jobs)
{
    __shared__ float AT[DIM * 132];
    __shared__ float Bs[DIM * 36];
    int4 jb = jobs.jb[blockIdx.x];
    int ncols = jb.w;
    int cpan = blockIdx.y * 32;
    if (cpan >= ncols) return;
    mm_body(ws + jb.x, ws + jb.y, ws + jb.z, ncols, cpan, AT, Bs);
}

// ---- Paterson-Stockmeyer epilogue: E1 = X4 @ q(X) + p(X) ------------------
// p = I + X + X^2/2 + X^3/6 ; q = I/24 + X/120 + X^2/720 + X^3/5040.
__global__ __launch_bounds__(256) void k_e1(float* __restrict__ ws)
{
    __shared__ float AT[DIM * 132];
    __shared__ float Bs[DIM * 36];
    const float* X1 = ws + XP(0);
    const float* X2 = ws + XP(1);
    const float* X3 = ws + XP(2);
    const float* X4 = ws + XP(3);
    float* E = ws + WOFFI(1);
    int tid = threadIdx.x, cpan = blockIdx.x * 32;
    for (int idx = tid; idx < DIM * DIM; idx += 256) {
        int d = idx >> 7, k = idx & 127;
        AT[k * 132 + d] = X4[idx];
    }
    const float q0 = 1.0f/24.0f, q1 = 1.0f/120.0f, q2 = 1.0f/720.0f, q3 = 1.0f/5040.0f;
    for (int idx = tid; idx < DIM * 32; idx += 256) {
        int k = idx >> 5, cc = idx & 31;
        int c = cpan + cc;
        size_t e = (size_t)k * DIM + c;
        float b = q1 * X1[e] + q2 * X2[e] + q3 * X3[e];
        if (k == c) b += q0;
        Bs[k * 36 + cc] = b;
    }
    __syncthreads();
    int td = tid & 31, tc = tid >> 5;
    int d0 = td * 4, c0 = tc * 4;
    float acc[4][4] = {};
    #pragma unroll 4
    for (int k = 0; k < DIM; k++) {
        float4 a4 = ld4(&AT[k * 132 + d0]);
        float4 b4 = ld4(&Bs[k * 36 + c0]);
        float a_[4] = {a4.x, a4.y, a4.z, a4.w};
        float b_[4] = {b4.x, b4.y, b4.z, b4.w};
        #pragma unroll
        for (int i = 0; i < 4; i++)
            #pragma unroll
            for (int j = 0; j < 4; j++) acc[i][j] += a_[i] * b_[j];
    }
    #pragma unroll
    for (int i = 0; i < 4; i++) {
        int d = d0 + i;
        #pragma unroll
        for (int j = 0; j < 4; j++) {
            int c = cpan + c0 + j;
            size_t e = (size_t)d * DIM + c;
            float v = acc[i][j] + X1[e] + 0.5f * X2[e] + (1.0f/6.0f) * X3[e];
            if (d == c) v += 1.0f;
            acc[i][j] = v;
        }
        float4 st = make_float4(acc[i][0], acc[i][1], acc[i][2], acc[i][3]);
        *(float4*)&E[(size_t)d * DIM + cpan + c0] = st;
    }
}

// ---- fused convert: W_i -> Wf frags, Y_j -> Yf frags ----------------------
__global__ __launch_bounds__(256) void k_conv(const float* __restrict__ ws,
                                              _Float16* __restrict__ Wf,
                                              _Float16* __restrict__ Yf)
{
    int g = blockIdx.x * 256 + threadIdx.x;          // 0 .. 196607
    if (g < 131072) {                                // W: 64 mats x 2048 chunks
        int i = g >> 11, c = g & 2047;
        int m = c >> 4, k0 = (c & 15) << 3;
        float v[8];
        if (i == 0) {
            #pragma unroll
            for (int q = 0; q < 8; q++) v[q] = (m == k0 + q) ? 1.0f : 0.0f;
        } else {
            const float* src = ws + WOFFI(i) + (size_t)m * DIM + k0;
            float4 a = ld4(src), b = ld4(src + 4);
            v[0]=a.x; v[1]=a.y; v[2]=a.z; v[3]=a.w; v[4]=b.x; v[5]=b.y; v[6]=b.z; v[7]=b.w;
        }
        f16x8 hv;
        #pragma unroll
        for (int q = 0; q < 8; q++) hv[q] = (_Float16)v[q];
        int lane = (m & 15) | (((k0 >> 3) & 3) << 4);
        size_t off = (size_t)i * 16384 + (((size_t)(m >> 4) * 4 + (k0 >> 5)) * 64 + lane) * 8;
        *(f16x8*)(Wf + off) = hv;
    } else {                                         // Y: 64 mats x 1024 chunks
        int g2 = g - 131072;
        int j = g2 >> 10, c = g2 & 1023;
        int n = c >> 4, k0 = (c & 15) << 3;
        const float* src = ws + YOFFI + (size_t)j * 8192 + n;
        f16x8 hv;
        #pragma unroll
        for (int q = 0; q < 8; q++) hv[q] = (_Float16)src[(size_t)(k0 + q) * 64];
        int lane = (n & 15) | (((k0 >> 3) & 3) << 4);
        size_t off = (size_t)j * 8192 + (((size_t)(n >> 4) * 4 + (k0 >> 5)) * 64 + lane) * 8;
        *(f16x8*)(Yf + off) = hv;
    }
}

// ---- final: out[64j+i] = W_i @ Y_j via MFMA (batch-major stores) ----------
__global__ __launch_bounds__(256) void k_final(const _Float16* __restrict__ Wf,
                                               const _Float16* __restrict__ Yf,
                                               float* __restrict__ out)
{
    int i = blockIdx.x, j = blockIdx.y;
    int tid = threadIdx.x, wave = tid >> 6, lane = tid & 63;
    const _Float16* Ab = Yf + (size_t)j * 8192;
    const _Float16* Bb = Wf + (size_t)i * 16384;
    f32x4 acc[4][2] = {};
    #pragma unroll
    for (int ks = 0; ks < 4; ks++) {
        f16x8 a[4], b[2];
        #pragma unroll
        for (int bt = 0; bt < 4; bt++)
            a[bt] = *(const f16x8*)(Ab + (((size_t)bt * 4 + ks) * 64 + lane) * 8);
        #pragma unroll
        for (int nn = 0; nn < 2; nn++)
            b[nn] = *(const f16x8*)(Bb + (((size_t)(wave * 2 + nn) * 4 + ks) * 64 + lane) * 8);
        #pragma unroll
        for (int bt = 0; bt < 4; bt++)
            #pragma unroll
            for (int nn = 0; nn < 2; nn++)
                acc[bt][nn] = __builtin_amdgcn_mfma_f32_16x16x32_f16(a[bt], b[nn], acc[bt][nn], 0, 0, 0);
    }
    float* slab = out + (size_t)(j * 64 + i) * 8192;
    int nlo = lane & 15, b0 = (lane >> 4) * 4;
    #pragma unroll
    for (int bt = 0; bt < 4; bt++)
        #pragma unroll
        for (int nn = 0; nn < 2; nn++) {
            int n = (wave * 2 + nn) * 16 + nlo;
            __builtin_nontemporal_store(acc[bt][nn],
                (f32x4*)&slab[(size_t)n * 64 + bt * 16 + b0]);
        }
}

static inline void addjob(Jobs& J, int& n, int a, int b, int c, int nc)
{
    J.jb[n++] = make_int4(a, b, c, nc);
}

extern "C" void kernel_launch(void* const* d_in, const int* in_sizes, int n_in,
                              void* d_out, int out_size, void* d_ws, size_t ws_size,
                              hipStream_t stream)
{
    const float* t  = (const float*)d_in[0];
    const float* x0 = (const float*)d_in[1];
    const float* S  = (const float*)d_in[2];
    const float* D  = (const float*)d_in[3];
    float* out = (float*)d_out;
    float* ws  = (float*)d_ws;
    _Float16* Wf = (_Float16*)(ws + FWOFFI);
    _Float16* Yf = (_Float16*)(ws + FYOFFI);

    hipLaunchKernelGGL(k_build, dim3(64), dim3(256), 0, stream, t, x0, S, D, ws);

    Jobs J; int n;

    // X2 = X*X
    n = 0; addjob(J, n, XP(0), XP(0), XP(1), 128);
    hipLaunchKernelGGL(k_lvl, dim3(n, 4), dim3(256), 0, stream, ws, J);
    // X3 = X2*X ; X4 = X2*X2
    n = 0;
    addjob(J, n, XP(1), XP(0), XP(2), 128);
    addjob(J, n, XP(1), XP(1), XP(3), 128);
    hipLaunchKernelGGL(k_lvl, dim3(n, 4), dim3(256), 0, stream, ws, J);
    // E1 = X4 @ q(X) + p(X)   (degree-7 Paterson-Stockmeyer)
    hipLaunchKernelGGL(k_e1, dim3(4), dim3(256), 0, stream, ws);

    // squaring chain with W-fill riding along
    // E2
    n = 0; addjob(J, n, WOFFI(1), WOFFI(1), WOFFI(2), 128);
    hipLaunchKernelGGL(k_lvl, dim3(n, 4), dim3(256), 0, stream, ws, J);
    // E4, E3
    n = 0;
    addjob(J, n, WOFFI(2), WOFFI(2), WOFFI(4), 128);
    addjob(J, n, WOFFI(2), WOFFI(1), WOFFI(3), 128);
    hipLaunchKernelGGL(k_lvl, dim3(n, 4), dim3(256), 0, stream, ws, J);
    // E8, E5..E7
    n = 0;
    addjob(J, n, WOFFI(4), WOFFI(4), WOFFI(8), 128);
    for (int r = 1; r <= 3; r++) addjob(J, n, WOFFI(4), WOFFI(r), WOFFI(4 + r), 128);
    hipLaunchKernelGGL(k_lvl, dim3(n, 4), dim3(256), 0, stream, ws, J);
    // E16, E9..E15
    n = 0;
    addjob(J, n, WOFFI(8), WOFFI(8), WOFFI(16), 128);
    for (int r = 1; r <= 7; r++) addjob(J, n, WOFFI(8), WOFFI(r), WOFFI(8 + r), 128);
    hipLaunchKernelGGL(k_lvl, dim3(n, 4), dim3(256), 0, stream, ws, J);
    // E32, E17..E31
    n = 0;
    addjob(J, n, WOFFI(16), WOFFI(16), WOFFI(32), 128);
    for (int r = 1; r <= 15; r++) addjob(J, n, WOFFI(16), WOFFI(r), WOFFI(16 + r), 128);
    hipLaunchKernelGGL(k_lvl, dim3(n, 4), dim3(256), 0, stream, ws, J);
    // E64 -> G0, E33..E63
    n = 0;
    addjob(J, n, WOFFI(32), WOFFI(32), GOFFI(0), 128);
    for (int r = 1; r <= 31; r++) addjob(J, n, WOFFI(32), WOFFI(r), WOFFI(32 + r), 128);
    hipLaunchKernelGGL(k_lvl, dim3(n, 4), dim3(256), 0, stream, ws, J);

    // Y doubling with G squarings riding along
    // G1 = E64^2 -> G1slot ; Y1 = E64 Y0
    n = 0;
    addjob(J, n, GOFFI(0), GOFFI(0), GOFFI(1), 128);
    addjob(J, n, GOFFI(0), YOFFI, YOFFI + 8192, 64);
    hipLaunchKernelGGL(k_lvl, dim3(n, 4), dim3(256), 0, stream, ws, J);
    // G2 -> G0 ; Y2,Y3
    n = 0;
    addjob(J, n, GOFFI(1), GOFFI(1), GOFFI(0), 128);
    addjob(J, n, GOFFI(1), YOFFI,        YOFFI + 2 * 8192, 64);
    addjob(J, n, GOFFI(1), YOFFI + 8192, YOFFI + 3 * 8192, 64);
    hipLaunchKernelGGL(k_lvl, dim3(n, 4), dim3(256), 0, stream, ws, J);
    // G3 -> G1 ; Y4..7
    n = 0;
    addjob(J, n, GOFFI(0), GOFFI(0), GOFFI(1), 128);
    for (int jj = 0; jj < 4; jj++)
        addjob(J, n, GOFFI(0), YOFFI + jj * 8192, YOFFI + (4 + jj) * 8192, 64);
    hipLaunchKernelGGL(k_lvl, dim3(n, 4), dim3(256), 0, stream, ws, J);
    // G4 -> G0 ; Y8..15
    n = 0;
    addjob(J, n, GOFFI(1), GOFFI(1), GOFFI(0), 128);
    for (int jj = 0; jj < 8; jj++)
        addjob(J, n, GOFFI(1), YOFFI + jj * 8192, YOFFI + (8 + jj) * 8192, 64);
    hipLaunchKernelGGL(k_lvl, dim3(n, 4), dim3(256), 0, stream, ws, J);
    // G5 -> G1 ; Y16..31
    n = 0;
    addjob(J, n, GOFFI(0), GOFFI(0), GOFFI(1), 128);
    for (int jj = 0; jj < 16; jj++)
        addjob(J, n, GOFFI(0), YOFFI + jj * 8192, YOFFI + (16 + jj) * 8192, 64);
    hipLaunchKernelGGL(k_lvl, dim3(n, 4), dim3(256), 0, stream, ws, J);
    // Y32..63 = G5 Y0..31
    n = 0;
    for (int jj = 0; jj < 32; jj++)
        addjob(J, n, GOFFI(1), YOFFI + jj * 8192, YOFFI + (32 + jj) * 8192, 64);
    hipLaunchKernelGGL(k_lvl, dim3(n, 4), dim3(256), 0, stream, ws, J);

    // convert all W,Y -> f16 fragment tables
    hipLaunchKernelGGL(k_conv, dim3(768), dim3(256), 0, stream, ws, Wf, Yf);

    // out[64j+i] = W_i @ Y_j
    hipLaunchKernelGGL(k_final, dim3(64, 64), dim3(256), 0, stream, Wf, Yf, out);
}